// Round 5
// baseline (558.863 us; speedup 1.0000x reference)
//
#include <hip/hip_runtime.h>
#include <cstdint>
#include <cstddef>

#define NN 8192
#define KFIN 1024
#define KFOUT 256
#define MAXD 192
#define LRALPHA 0.2f

typedef float f32x4 __attribute__((ext_vector_type(4)));

// ---------------------------------------------------------------------------
// Kernel A: dense adj -> CSR neighbor lists (stable ascending-column order via
// 4x ballot on float4 nontemporal loads), degree, s2 = off-diagonal degree.
// ---------------------------------------------------------------------------
__global__ void __launch_bounds__(256) k_build_csr(
    const float* __restrict__ adj, int* __restrict__ nbr,
    int* __restrict__ deg, int* __restrict__ s2v) {
  const int wave = threadIdx.x >> 6;
  const int lane = threadIdx.x & 63;
  const int row = blockIdx.x * 4 + wave;
  const float* arow = adj + (size_t)row * NN;
  int* outp = nbr + (size_t)row * MAXD;
  int count = 0;
  int dflag = 0;
  const unsigned long long below = (1ull << lane) - 1ull;
  for (int c0 = 0; c0 < NN; c0 += 256) {
    const int c = c0 + lane * 4;
    const f32x4 v = __builtin_nontemporal_load(
        reinterpret_cast<const f32x4*>(arow + c));
    const unsigned long long m0 = __ballot(v[0] > 0.0f);
    const unsigned long long m1 = __ballot(v[1] > 0.0f);
    const unsigned long long m2 = __ballot(v[2] > 0.0f);
    const unsigned long long m3 = __ballot(v[3] > 0.0f);
    int pos = count + (int)(__popcll(m0 & below) + __popcll(m1 & below) +
                            __popcll(m2 & below) + __popcll(m3 & below));
    if (v[0] > 0.0f) { if (pos < MAXD) outp[pos] = c + 0; ++pos; if (c + 0 == row) dflag = 1; }
    if (v[1] > 0.0f) { if (pos < MAXD) outp[pos] = c + 1; ++pos; if (c + 1 == row) dflag = 1; }
    if (v[2] > 0.0f) { if (pos < MAXD) outp[pos] = c + 2; ++pos; if (c + 2 == row) dflag = 1; }
    if (v[3] > 0.0f) { if (pos < MAXD) outp[pos] = c + 3; ++pos; if (c + 3 == row) dflag = 1; }
    count += (int)(__popcll(m0) + __popcll(m1) + __popcll(m2) + __popcll(m3));
  }
  const int anyd = __any(dflag) ? 1 : 0;
  if (lane == 0) {
    deg[row] = count < MAXD ? count : MAXD;
    s2v[row] = count - anyd;
  }
}

// ---------------------------------------------------------------------------
// Kernel B: Wh = h @ W, f32 tiled GEMM (64x64 tile, 4x4 per thread, BK=16).
// ---------------------------------------------------------------------------
__global__ void __launch_bounds__(256) k_gemm(
    const float* __restrict__ A, const float* __restrict__ B,
    float* __restrict__ C) {
  __shared__ float As[16][65];
  __shared__ float Bs[16][65];
  const int tid = threadIdx.x;
  const int brow = blockIdx.y * 64;
  const int bcol = blockIdx.x * 64;
  const int tx = tid & 15;
  const int ty = tid >> 4;
  float acc[4][4];
#pragma unroll
  for (int i = 0; i < 4; ++i)
#pragma unroll
    for (int j = 0; j < 4; ++j) acc[i][j] = 0.0f;
  const int ar = tid >> 2;
  const int ac = (tid & 3) << 2;
  const int br = tid >> 4;
  const int bc = (tid & 15) << 2;
  for (int k0 = 0; k0 < KFIN; k0 += 16) {
    const float4 av =
        *reinterpret_cast<const float4*>(A + (size_t)(brow + ar) * KFIN + k0 + ac);
    const float4 bv =
        *reinterpret_cast<const float4*>(B + (size_t)(k0 + br) * KFOUT + bcol + bc);
    As[ac + 0][ar] = av.x;
    As[ac + 1][ar] = av.y;
    As[ac + 2][ar] = av.z;
    As[ac + 3][ar] = av.w;
    Bs[br][bc + 0] = bv.x;
    Bs[br][bc + 1] = bv.y;
    Bs[br][bc + 2] = bv.z;
    Bs[br][bc + 3] = bv.w;
    __syncthreads();
#pragma unroll
    for (int kk = 0; kk < 16; ++kk) {
      const float a0 = As[kk][ty * 4 + 0];
      const float a1 = As[kk][ty * 4 + 1];
      const float a2 = As[kk][ty * 4 + 2];
      const float a3 = As[kk][ty * 4 + 3];
      const float b0 = Bs[kk][tx * 4 + 0];
      const float b1 = Bs[kk][tx * 4 + 1];
      const float b2 = Bs[kk][tx * 4 + 2];
      const float b3 = Bs[kk][tx * 4 + 3];
      acc[0][0] += a0 * b0; acc[0][1] += a0 * b1; acc[0][2] += a0 * b2; acc[0][3] += a0 * b3;
      acc[1][0] += a1 * b0; acc[1][1] += a1 * b1; acc[1][2] += a1 * b2; acc[1][3] += a1 * b3;
      acc[2][0] += a2 * b0; acc[2][1] += a2 * b1; acc[2][2] += a2 * b2; acc[2][3] += a2 * b3;
      acc[3][0] += a3 * b0; acc[3][1] += a3 * b1; acc[3][2] += a3 * b2; acc[3][3] += a3 * b3;
    }
    __syncthreads();
  }
#pragma unroll
  for (int i = 0; i < 4; ++i) {
#pragma unroll
    for (int j = 0; j < 4; ++j) {
      C[(size_t)(brow + ty * 4 + i) * KFOUT + bcol + tx * 4 + j] = acc[i][j];
    }
  }
}

// ---------------------------------------------------------------------------
// Kernel C: Wh1 = Wh @ a[:256], Wh2 = Wh @ a[256:], one block per row.
// ---------------------------------------------------------------------------
__global__ void __launch_bounds__(256) k_rowdots(
    const float* __restrict__ Wh, const float* __restrict__ a,
    float* __restrict__ Wh1, float* __restrict__ Wh2) {
  __shared__ float sA[256];
  __shared__ float sB[256];
  const int row = blockIdx.x;
  const int t = threadIdx.x;
  const float w = Wh[(size_t)row * KFOUT + t];
  sA[t] = w * a[t];
  sB[t] = w * a[KFOUT + t];
  __syncthreads();
  for (int s = 128; s > 0; s >>= 1) {
    if (t < s) {
      sA[t] += sA[t + s];
      sB[t] += sB[t + s];
    }
    __syncthreads();
  }
  if (t == 0) {
    Wh1[row] = sA[0];
    Wh2[row] = sB[0];
  }
}

// ---------------------------------------------------------------------------
// Kernel D1: per-row softmax stats (max m, denom Z) over neighbor list.
// ---------------------------------------------------------------------------
__global__ void __launch_bounds__(256) k_stats(
    const int* __restrict__ nbr, const int* __restrict__ deg,
    const float* __restrict__ Wh1, const float* __restrict__ Wh2,
    float* __restrict__ mrow, float* __restrict__ Zrow) {
  const int wave = threadIdx.x >> 6;
  const int lane = threadIdx.x & 63;
  const int row = blockIdx.x * 4 + wave;
  const int d = deg[row];
  const int* cols = nbr + (size_t)row * MAXD;
  const float w1 = Wh1[row];
  float mx = -1e30f;
  for (int t = lane; t < d; t += 64) {
    float e = w1 + Wh2[cols[t]];
    e = e > 0.0f ? e : LRALPHA * e;
    mx = fmaxf(mx, e);
  }
  for (int o = 32; o > 0; o >>= 1) mx = fmaxf(mx, __shfl_xor(mx, o));
  float sum = 0.0f;
  for (int t = lane; t < d; t += 64) {
    float e = w1 + Wh2[cols[t]];
    e = e > 0.0f ? e : LRALPHA * e;
    sum += expf(e - mx);
  }
  for (int o = 32; o > 0; o >>= 1) sum += __shfl_xor(sum, o);
  if (lane == 0) {
    mrow[row] = mx;
    Zrow[row] = (d > 0) ? sum : 1.0f;
  }
}

// ---------------------------------------------------------------------------
// Kernel D2: attention CSR values + packed transpose-edge values + per-row
// column-OCTANT split counts (cols ascending -> octants contiguous).
// qb8[row][m-1] = count(col < m*1024) for m=1..7; qb8[row][7] = d.
// ---------------------------------------------------------------------------
__global__ void __launch_bounds__(256) k_att(
    const int* __restrict__ nbr, const int* __restrict__ deg,
    const float* __restrict__ Wh1, const float* __restrict__ Wh2,
    const float* __restrict__ mrow, const float* __restrict__ Zrow,
    float* __restrict__ att, int2* __restrict__ edgesT,
    short* __restrict__ qb8) {
  const int wave = threadIdx.x >> 6;
  const int lane = threadIdx.x & 63;
  const int row = blockIdx.x * 4 + wave;
  const int d = deg[row];
  const int* cols = nbr + (size_t)row * MAXD;
  const float w1r = Wh1[row];
  const float w2r = Wh2[row];
  const float mr = mrow[row];
  const float invZr = 1.0f / Zrow[row];
  int b[7] = {0, 0, 0, 0, 0, 0, 0};
  for (int t0 = 0; t0 < d; t0 += 64) {
    const int t = t0 + lane;
    const bool act = t < d;
    const int j = act ? cols[t] : 0x7fffffff;
#pragma unroll
    for (int m = 1; m <= 7; ++m)
      b[m - 1] += (int)__popcll(__ballot(act && j < m * 1024));
    if (act) {
      float e = w1r + Wh2[j];
      e = e > 0.0f ? e : LRALPHA * e;
      att[(size_t)row * MAXD + t] = expf(e - mr) * invZr;
      float e2 = Wh1[j] + w2r;
      e2 = e2 > 0.0f ? e2 : LRALPHA * e2;
      const float v = expf(e2 - mrow[j]) / Zrow[j];
      edgesT[(size_t)row * MAXD + t] = make_int2(j, __float_as_int(v));
    }
  }
  if (lane == 0) {
    short* q = qb8 + (size_t)row * 8;
    q[0] = (short)b[0]; q[1] = (short)b[1]; q[2] = (short)b[2]; q[3] = (short)b[3];
    q[4] = (short)b[4]; q[5] = (short)b[5]; q[6] = (short)b[6]; q[7] = (short)d;
  }
}

// ---------------------------------------------------------------------------
// Kernel E: per row i, 512 threads (8 waves), comb row in LDS.
// Octant-partitioned FLATTENED scatter: wave w owns cols [w*1024,(w+1)*1024).
// Per wave: prefix-sum over its octant segment lengths, then iterate the
// flattened edge stream 64 edges/step at full lane utilization (bsearch for
// (neighbor, offset), depth-2 pipelined global loads, ds_add_f32 into comb).
// Wave-internal atomics only -> replay-deterministic. Then vectorized radix
// select of the s2-th largest (zeros skipped) and binary row emit.
// ---------------------------------------------------------------------------
__global__ void __launch_bounds__(512) k_twostep(
    const int* __restrict__ nbr, const int* __restrict__ deg,
    const int* __restrict__ s2v, const float* __restrict__ att,
    const int2* __restrict__ edgesT, const short* __restrict__ qb8,
    float* __restrict__ out1) {
  __shared__ float comb[NN];
  __shared__ float wvals[MAXD];
  __shared__ int kcols[MAXD];
  __shared__ short sqb[MAXD][8];
  __shared__ int pfx[8][MAXD + 1];
  __shared__ unsigned int hist[256];
  __shared__ unsigned int shPrefix;
  __shared__ int shRemaining;
  const int tid = threadIdx.x;
  const int wave = tid >> 6;
  const int lane = tid & 63;
  const int row = blockIdx.x;
  const f32x4 z4 = {0.0f, 0.0f, 0.0f, 0.0f};
  for (int j = tid * 4; j < NN; j += 2048)
    *reinterpret_cast<f32x4*>(&comb[j]) = z4;
  const int d = deg[row];
  const int* cols = nbr + (size_t)row * MAXD;
  const float* arow = att + (size_t)row * MAXD;
  for (int t = tid; t < d; t += 512) {
    const int c = cols[t];
    kcols[t] = c;
    wvals[t] = arow[t];
    *reinterpret_cast<int4*>(&sqb[t][0]) =
        *reinterpret_cast<const int4*>(&qb8[(size_t)c * 8]);
  }
  __syncthreads();
  // --- per-wave prefix over octant segment lengths (wave-local, no barrier)
  int run = 0;
  for (int t0 = 0; t0 < d; t0 += 64) {
    const int t = t0 + lane;
    int len = 0;
    if (t < d) {
      const int lo = wave ? (int)sqb[t][wave - 1] : 0;
      len = (int)sqb[t][wave] - lo;
    }
    int scan = len;
#pragma unroll
    for (int o = 1; o < 64; o <<= 1) {
      const int v = __shfl_up(scan, o);
      if (lane >= o) scan += v;
    }
    if (t < d) pfx[wave][t + 1] = run + scan;
    run += __shfl(scan, 63);
  }
  if (lane == 0) pfx[wave][0] = 0;
  const int Ew = run;
  // --- flattened scatter, depth-2 pipeline
  {
    const int* pw = pfx[wave];
    int2 eA = make_int2(0, 0), eB = make_int2(0, 0);
    float wA = 0.0f, wB = 0.0f;
    bool aA = false, aB = false;
#define TS_ISSUE(E_, W_, A_, BASE)                                    \
    {                                                                  \
      const int eidx = (BASE) + lane;                                  \
      A_ = eidx < Ew;                                                  \
      const int ei = A_ ? eidx : 0;                                    \
      int lo = 0, hi = d - 1;                                          \
      while (lo < hi) {                                                \
        const int mid = (lo + hi + 1) >> 1;                            \
        if (pw[mid] <= ei) lo = mid; else hi = mid - 1;                \
      }                                                                \
      const int off = ei - pw[lo];                                     \
      const int qs = wave ? (int)sqb[lo][wave - 1] : 0;                \
      W_ = wvals[lo];                                                  \
      E_ = make_int2(0, 0);                                            \
      if (A_) E_ = edgesT[(size_t)kcols[lo] * MAXD + qs + off];        \
    }
    if (Ew > 0) TS_ISSUE(eA, wA, aA, 0);
    if (Ew > 64) TS_ISSUE(eB, wB, aB, 64);
    for (int base = 0; base < Ew; base += 64) {
      const int2 e = eA; const float w = wA; const bool a = aA;
      eA = eB; wA = wB; aA = aB;
      if (base + 128 < Ew) TS_ISSUE(eB, wB, aB, base + 128);
      if (a) atomicAdd(&comb[e.x], w * __int_as_float(e.y));
    }
#undef TS_ISSUE
  }
  // --- add row's own attention values (wave's own octant segment; distinct
  //     addresses within the wave -> plain RMW, deterministic)
  {
    const short* qr = qb8 + (size_t)row * 8;
    const int qlo = wave ? (int)qr[wave - 1] : 0;
    const int qhi = (int)qr[wave];
    for (int t = qlo + lane; t < qhi; t += 64) comb[kcols[t]] += wvals[t];
  }
  __syncthreads();
  if (tid == 0) comb[row] = 0.0f;
  __syncthreads();
  const int kk = s2v[row];
  const size_t obase = (size_t)row * NN;
  if (kk <= 0) {
    for (int j = tid * 4; j < NN; j += 2048)
      __builtin_nontemporal_store(z4, reinterpret_cast<f32x4*>(&out1[obase + j]));
    return;
  }
  // --- radix select: kk-th largest of comb. All values >= 0 -> uint order.
  // Threshold provably > 0, so zero entries are skipped.
  unsigned int prefix = 0u;
  int remaining = kk;
  for (int pass = 0; pass < 4; ++pass) {
    const int shift = 24 - 8 * pass;
    const unsigned int pmask = (pass == 0) ? 0u : (0xFFFFFFFFu << (shift + 8));
    if (tid < 256) hist[tid] = 0u;
    __syncthreads();
    for (int j = tid * 4; j < NN; j += 2048) {
      const f32x4 cv = *reinterpret_cast<const f32x4*>(&comb[j]);
#pragma unroll
      for (int q = 0; q < 4; ++q) {
        const unsigned int u = __float_as_uint(cv[q]);
        if (u != 0u && (u & pmask) == prefix)
          atomicAdd(&hist[(u >> shift) & 255u], 1u);
      }
    }
    __syncthreads();
    if (tid < 64) {
      const int bHi = 255 - 4 * lane;  // lane 0 owns highest bins
      const unsigned int c0 = hist[bHi];
      const unsigned int c1 = hist[bHi - 1];
      const unsigned int c2 = hist[bHi - 2];
      const unsigned int c3 = hist[bHi - 3];
      const unsigned int gs = c0 + c1 + c2 + c3;
      unsigned int run2 = gs;
      for (int o = 1; o < 64; o <<= 1) {
        const unsigned int tt = __shfl_up(run2, o);
        if (lane >= o) run2 += tt;
      }
      const unsigned int pre = run2 - gs;  // count in strictly higher bins
      const unsigned int rem = (unsigned int)remaining;
      if (pre < rem && pre + gs >= rem) {  // exactly one lane hits
        unsigned int above;
        int digit;
        if (pre + c0 >= rem) { digit = bHi; above = pre; }
        else if (pre + c0 + c1 >= rem) { digit = bHi - 1; above = pre + c0; }
        else if (pre + c0 + c1 + c2 >= rem) { digit = bHi - 2; above = pre + c0 + c1; }
        else { digit = bHi - 3; above = pre + c0 + c1 + c2; }
        shPrefix = prefix | ((unsigned int)digit << shift);
        shRemaining = remaining - (int)above;
      }
    }
    __syncthreads();
    prefix = shPrefix;
    remaining = shRemaining;
    __syncthreads();
  }
  const float thr = __uint_as_float(prefix);  // exact kk-th largest value
  for (int j = tid * 4; j < NN; j += 2048) {
    const f32x4 cv = *reinterpret_cast<const f32x4*>(&comb[j]);
    f32x4 ov;
    ov[0] = (cv[0] >= thr && cv[0] > 0.0f) ? 1.0f : 0.0f;
    ov[1] = (cv[1] >= thr && cv[1] > 0.0f) ? 1.0f : 0.0f;
    ov[2] = (cv[2] >= thr && cv[2] > 0.0f) ? 1.0f : 0.0f;
    ov[3] = (cv[3] >= thr && cv[3] > 0.0f) ? 1.0f : 0.0f;
    __builtin_nontemporal_store(ov, reinterpret_cast<f32x4*>(&out1[obase + j]));
  }
}

// ---------------------------------------------------------------------------
// Kernel F: h_prime = attention @ Wh (sparse x dense), then ELU.
// ---------------------------------------------------------------------------
__global__ void __launch_bounds__(256) k_hprime(
    const int* __restrict__ nbr, const int* __restrict__ deg,
    const float* __restrict__ att, const float* __restrict__ Wh,
    float* __restrict__ out0) {
  __shared__ int scol[MAXD];
  __shared__ float sval[MAXD];
  const int row = blockIdx.x;
  const int c = threadIdx.x;
  const int d = deg[row];
  const int* cols = nbr + (size_t)row * MAXD;
  const float* arow = att + (size_t)row * MAXD;
  for (int t = threadIdx.x; t < d; t += 256) {
    scol[t] = cols[t];
    sval[t] = arow[t];
  }
  __syncthreads();
  float a0 = 0.0f, a1 = 0.0f, a2 = 0.0f, a3 = 0.0f;
  int t = 0;
  for (; t + 4 <= d; t += 4) {
    a0 += sval[t + 0] * Wh[(size_t)scol[t + 0] * KFOUT + c];
    a1 += sval[t + 1] * Wh[(size_t)scol[t + 1] * KFOUT + c];
    a2 += sval[t + 2] * Wh[(size_t)scol[t + 2] * KFOUT + c];
    a3 += sval[t + 3] * Wh[(size_t)scol[t + 3] * KFOUT + c];
  }
  for (; t < d; ++t) a0 += sval[t] * Wh[(size_t)scol[t] * KFOUT + c];
  const float acc = (a0 + a1) + (a2 + a3);
  out0[(size_t)row * KFOUT + c] = acc > 0.0f ? acc : expm1f(acc);
}

extern "C" void kernel_launch(void* const* d_in, const int* in_sizes, int n_in,
                              void* d_out, int out_size, void* d_ws, size_t ws_size,
                              hipStream_t stream) {
  const float* h = (const float*)d_in[0];
  const float* adj = (const float*)d_in[1];
  const float* W = (const float*)d_in[2];
  const float* a = (const float*)d_in[3];

  float* out0 = (float*)d_out;                  // [8192, 256] elu(h_prime)
  float* out1 = out0 + (size_t)NN * KFOUT;      // [8192, 8192] adj_resize

  // workspace layout (~33.9 MB)
  float* Wh = (float*)d_ws;                        // 8192*256
  float* Wh1 = Wh + (size_t)NN * KFOUT;            // 8192
  float* Wh2 = Wh1 + NN;                           // 8192
  float* mrow = Wh2 + NN;                          // 8192
  float* Zrow = mrow + NN;                         // 8192
  float* att = Zrow + NN;                          // 8192*MAXD
  float* edgesF = att + (size_t)NN * MAXD;         // 8192*MAXD int2
  int2* edgesT = (int2*)edgesF;
  int* nbr = (int*)(edgesF + (size_t)NN * MAXD * 2);  // 8192*MAXD
  int* deg = nbr + (size_t)NN * MAXD;              // 8192
  int* s2v = deg + NN;                             // 8192
  short* qb8 = (short*)(s2v + NN);                 // 8192*8 shorts (128 KB)

  k_build_csr<<<NN / 4, 256, 0, stream>>>(adj, nbr, deg, s2v);
  dim3 ggrid(KFOUT / 64, NN / 64);
  k_gemm<<<ggrid, 256, 0, stream>>>(h, W, Wh);
  k_rowdots<<<NN, 256, 0, stream>>>(Wh, a, Wh1, Wh2);
  k_stats<<<NN / 4, 256, 0, stream>>>(nbr, deg, Wh1, Wh2, mrow, Zrow);
  k_att<<<NN / 4, 256, 0, stream>>>(nbr, deg, Wh1, Wh2, mrow, Zrow, att, edgesT, qb8);
  k_twostep<<<NN, 512, 0, stream>>>(nbr, deg, s2v, att, edgesT, qb8, out1);
  k_hprime<<<NN, 256, 0, stream>>>(nbr, deg, att, Wh, out0);
}

// Round 6
// 487.299 us; speedup vs baseline: 1.1469x; 1.1469x over previous
//
#include <hip/hip_runtime.h>
#include <cstdint>
#include <cstddef>

#define NN 8192
#define KFIN 1024
#define KFOUT 256
#define MAXD 192
#define LRALPHA 0.2f

typedef float f32x4 __attribute__((ext_vector_type(4)));

// ---------------------------------------------------------------------------
// Kernel A: dense adj -> CSR neighbor lists (stable ascending-column order via
// 4x ballot on float4 nontemporal loads), degree, s2 = off-diagonal degree.
// ---------------------------------------------------------------------------
__global__ void __launch_bounds__(256) k_build_csr(
    const float* __restrict__ adj, int* __restrict__ nbr,
    int* __restrict__ deg, int* __restrict__ s2v) {
  const int wave = threadIdx.x >> 6;
  const int lane = threadIdx.x & 63;
  const int row = blockIdx.x * 4 + wave;
  const float* arow = adj + (size_t)row * NN;
  int* outp = nbr + (size_t)row * MAXD;
  int count = 0;
  int dflag = 0;
  const unsigned long long below = (1ull << lane) - 1ull;
  for (int c0 = 0; c0 < NN; c0 += 256) {
    const int c = c0 + lane * 4;
    const f32x4 v = __builtin_nontemporal_load(
        reinterpret_cast<const f32x4*>(arow + c));
    const unsigned long long m0 = __ballot(v[0] > 0.0f);
    const unsigned long long m1 = __ballot(v[1] > 0.0f);
    const unsigned long long m2 = __ballot(v[2] > 0.0f);
    const unsigned long long m3 = __ballot(v[3] > 0.0f);
    int pos = count + (int)(__popcll(m0 & below) + __popcll(m1 & below) +
                            __popcll(m2 & below) + __popcll(m3 & below));
    if (v[0] > 0.0f) { if (pos < MAXD) outp[pos] = c + 0; ++pos; if (c + 0 == row) dflag = 1; }
    if (v[1] > 0.0f) { if (pos < MAXD) outp[pos] = c + 1; ++pos; if (c + 1 == row) dflag = 1; }
    if (v[2] > 0.0f) { if (pos < MAXD) outp[pos] = c + 2; ++pos; if (c + 2 == row) dflag = 1; }
    if (v[3] > 0.0f) { if (pos < MAXD) outp[pos] = c + 3; ++pos; if (c + 3 == row) dflag = 1; }
    count += (int)(__popcll(m0) + __popcll(m1) + __popcll(m2) + __popcll(m3));
  }
  const int anyd = __any(dflag) ? 1 : 0;
  if (lane == 0) {
    deg[row] = count < MAXD ? count : MAXD;
    s2v[row] = count - anyd;
  }
}

// ---------------------------------------------------------------------------
// Kernel B: Wh = h @ W, f32 tiled GEMM (64x64 tile, 4x4 per thread, BK=16).
// ---------------------------------------------------------------------------
__global__ void __launch_bounds__(256) k_gemm(
    const float* __restrict__ A, const float* __restrict__ B,
    float* __restrict__ C) {
  __shared__ float As[16][65];
  __shared__ float Bs[16][65];
  const int tid = threadIdx.x;
  const int brow = blockIdx.y * 64;
  const int bcol = blockIdx.x * 64;
  const int tx = tid & 15;
  const int ty = tid >> 4;
  float acc[4][4];
#pragma unroll
  for (int i = 0; i < 4; ++i)
#pragma unroll
    for (int j = 0; j < 4; ++j) acc[i][j] = 0.0f;
  const int ar = tid >> 2;
  const int ac = (tid & 3) << 2;
  const int br = tid >> 4;
  const int bc = (tid & 15) << 2;
  for (int k0 = 0; k0 < KFIN; k0 += 16) {
    const float4 av =
        *reinterpret_cast<const float4*>(A + (size_t)(brow + ar) * KFIN + k0 + ac);
    const float4 bv =
        *reinterpret_cast<const float4*>(B + (size_t)(k0 + br) * KFOUT + bcol + bc);
    As[ac + 0][ar] = av.x;
    As[ac + 1][ar] = av.y;
    As[ac + 2][ar] = av.z;
    As[ac + 3][ar] = av.w;
    Bs[br][bc + 0] = bv.x;
    Bs[br][bc + 1] = bv.y;
    Bs[br][bc + 2] = bv.z;
    Bs[br][bc + 3] = bv.w;
    __syncthreads();
#pragma unroll
    for (int kk = 0; kk < 16; ++kk) {
      const float a0 = As[kk][ty * 4 + 0];
      const float a1 = As[kk][ty * 4 + 1];
      const float a2 = As[kk][ty * 4 + 2];
      const float a3 = As[kk][ty * 4 + 3];
      const float b0 = Bs[kk][tx * 4 + 0];
      const float b1 = Bs[kk][tx * 4 + 1];
      const float b2 = Bs[kk][tx * 4 + 2];
      const float b3 = Bs[kk][tx * 4 + 3];
      acc[0][0] += a0 * b0; acc[0][1] += a0 * b1; acc[0][2] += a0 * b2; acc[0][3] += a0 * b3;
      acc[1][0] += a1 * b0; acc[1][1] += a1 * b1; acc[1][2] += a1 * b2; acc[1][3] += a1 * b3;
      acc[2][0] += a2 * b0; acc[2][1] += a2 * b1; acc[2][2] += a2 * b2; acc[2][3] += a2 * b3;
      acc[3][0] += a3 * b0; acc[3][1] += a3 * b1; acc[3][2] += a3 * b2; acc[3][3] += a3 * b3;
    }
    __syncthreads();
  }
#pragma unroll
  for (int i = 0; i < 4; ++i) {
#pragma unroll
    for (int j = 0; j < 4; ++j) {
      C[(size_t)(brow + ty * 4 + i) * KFOUT + bcol + tx * 4 + j] = acc[i][j];
    }
  }
}

// ---------------------------------------------------------------------------
// Kernel C: Wh1 = Wh @ a[:256], Wh2 = Wh @ a[256:], one block per row.
// ---------------------------------------------------------------------------
__global__ void __launch_bounds__(256) k_rowdots(
    const float* __restrict__ Wh, const float* __restrict__ a,
    float* __restrict__ Wh1, float* __restrict__ Wh2) {
  __shared__ float sA[256];
  __shared__ float sB[256];
  const int row = blockIdx.x;
  const int t = threadIdx.x;
  const float w = Wh[(size_t)row * KFOUT + t];
  sA[t] = w * a[t];
  sB[t] = w * a[KFOUT + t];
  __syncthreads();
  for (int s = 128; s > 0; s >>= 1) {
    if (t < s) {
      sA[t] += sA[t + s];
      sB[t] += sB[t + s];
    }
    __syncthreads();
  }
  if (t == 0) {
    Wh1[row] = sA[0];
    Wh2[row] = sB[0];
  }
}

// ---------------------------------------------------------------------------
// Kernel D1: per-row softmax stats (max m, denom Z) over neighbor list.
// ---------------------------------------------------------------------------
__global__ void __launch_bounds__(256) k_stats(
    const int* __restrict__ nbr, const int* __restrict__ deg,
    const float* __restrict__ Wh1, const float* __restrict__ Wh2,
    float* __restrict__ mrow, float* __restrict__ Zrow) {
  const int wave = threadIdx.x >> 6;
  const int lane = threadIdx.x & 63;
  const int row = blockIdx.x * 4 + wave;
  const int d = deg[row];
  const int* cols = nbr + (size_t)row * MAXD;
  const float w1 = Wh1[row];
  float mx = -1e30f;
  for (int t = lane; t < d; t += 64) {
    float e = w1 + Wh2[cols[t]];
    e = e > 0.0f ? e : LRALPHA * e;
    mx = fmaxf(mx, e);
  }
  for (int o = 32; o > 0; o >>= 1) mx = fmaxf(mx, __shfl_xor(mx, o));
  float sum = 0.0f;
  for (int t = lane; t < d; t += 64) {
    float e = w1 + Wh2[cols[t]];
    e = e > 0.0f ? e : LRALPHA * e;
    sum += expf(e - mx);
  }
  for (int o = 32; o > 0; o >>= 1) sum += __shfl_xor(sum, o);
  if (lane == 0) {
    mrow[row] = mx;
    Zrow[row] = (d > 0) ? sum : 1.0f;
  }
}

// ---------------------------------------------------------------------------
// Kernel D2: attention CSR values + packed transpose-edge values + per-row
// column-OCTANT split counts (cols ascending -> octants contiguous).
// qb8[row][m-1] = count(col < m*1024) for m=1..7; qb8[row][7] = d.
// ---------------------------------------------------------------------------
__global__ void __launch_bounds__(256) k_att(
    const int* __restrict__ nbr, const int* __restrict__ deg,
    const float* __restrict__ Wh1, const float* __restrict__ Wh2,
    const float* __restrict__ mrow, const float* __restrict__ Zrow,
    float* __restrict__ att, int2* __restrict__ edgesT,
    short* __restrict__ qb8) {
  const int wave = threadIdx.x >> 6;
  const int lane = threadIdx.x & 63;
  const int row = blockIdx.x * 4 + wave;
  const int d = deg[row];
  const int* cols = nbr + (size_t)row * MAXD;
  const float w1r = Wh1[row];
  const float w2r = Wh2[row];
  const float mr = mrow[row];
  const float invZr = 1.0f / Zrow[row];
  int b[7] = {0, 0, 0, 0, 0, 0, 0};
  for (int t0 = 0; t0 < d; t0 += 64) {
    const int t = t0 + lane;
    const bool act = t < d;
    const int j = act ? cols[t] : 0x7fffffff;
#pragma unroll
    for (int m = 1; m <= 7; ++m)
      b[m - 1] += (int)__popcll(__ballot(act && j < m * 1024));
    if (act) {
      float e = w1r + Wh2[j];
      e = e > 0.0f ? e : LRALPHA * e;
      att[(size_t)row * MAXD + t] = expf(e - mr) * invZr;
      float e2 = Wh1[j] + w2r;
      e2 = e2 > 0.0f ? e2 : LRALPHA * e2;
      const float v = expf(e2 - mrow[j]) / Zrow[j];
      edgesT[(size_t)row * MAXD + t] = make_int2(j, __float_as_int(v));
    }
  }
  if (lane == 0) {
    short* q = qb8 + (size_t)row * 8;
    q[0] = (short)b[0]; q[1] = (short)b[1]; q[2] = (short)b[2]; q[3] = (short)b[3];
    q[4] = (short)b[4]; q[5] = (short)b[5]; q[6] = (short)b[6]; q[7] = (short)d;
  }
}

// ---------------------------------------------------------------------------
// Kernel E: per row i, 512 threads (8 waves), comb row in LDS.
// Octant-partitioned scatter with 8-lane GROUP expansion: wave w owns cols
// [w*1024,(w+1)*1024); per wave-step, group g (= lane>>3) processes neighbor
// t0+g's octant segment directly from the staged sqb table (no prefix scan,
// no bsearch). Cross-group collisions use LDS atomicAdd (wave-internal, HW
// lane-order -> replay-deterministic). Then vectorized radix select of the
// s2-th largest (zeros skipped) and binary row emit with nt stores.
// LDS = 38.4 KB -> 4 blocks/CU -> 32 waves/CU.
// ---------------------------------------------------------------------------
__global__ void __launch_bounds__(512) k_twostep(
    const int* __restrict__ nbr, const int* __restrict__ deg,
    const int* __restrict__ s2v, const float* __restrict__ att,
    const int2* __restrict__ edgesT, const short* __restrict__ qb8,
    float* __restrict__ out1) {
  __shared__ float comb[NN];
  __shared__ float wvals[MAXD];
  __shared__ int kcols[MAXD];
  __shared__ short sqb[MAXD][8];
  __shared__ unsigned int hist[256];
  __shared__ unsigned int shPrefix;
  __shared__ int shRemaining;
  const int tid = threadIdx.x;
  const int wave = tid >> 6;
  const int lane = tid & 63;
  const int row = blockIdx.x;
  const f32x4 z4 = {0.0f, 0.0f, 0.0f, 0.0f};
  for (int j = tid * 4; j < NN; j += 2048)
    *reinterpret_cast<f32x4*>(&comb[j]) = z4;
  const int d = deg[row];
  const int* cols = nbr + (size_t)row * MAXD;
  const float* arow = att + (size_t)row * MAXD;
  for (int t = tid; t < d; t += 512) {
    const int c = cols[t];
    kcols[t] = c;
    wvals[t] = arow[t];
    *reinterpret_cast<int4*>(&sqb[t][0]) =
        *reinterpret_cast<const int4*>(&qb8[(size_t)c * 8]);
  }
  __syncthreads();
  // --- group-expanded scatter: 8 groups x 8 lanes per wave
  {
    const int grp = lane >> 3;   // 0..7: which neighbor within the batch
    const int sub = lane & 7;    // 0..7: offset within the segment
    for (int t0 = 0; t0 < d; t0 += 8) {
      const int t = t0 + grp;
      if (t < d) {
        const int qs = wave ? (int)sqb[t][wave - 1] : 0;
        const int qe = (int)sqb[t][wave];
        const float w = wvals[t];
        const int2* ek = edgesT + (size_t)kcols[t] * MAXD;
        for (int off = qs + sub; off < qe; off += 8) {
          const int2 e = ek[off];
          atomicAdd(&comb[e.x], w * __int_as_float(e.y));
        }
      }
    }
  }
  // --- add row's own attention values (wave's own octant segment; distinct
  //     addresses within the wave -> plain RMW, deterministic)
  {
    const short* qr = qb8 + (size_t)row * 8;
    const int qlo = wave ? (int)qr[wave - 1] : 0;
    const int qhi = (int)qr[wave];
    for (int t = qlo + lane; t < qhi; t += 64) comb[kcols[t]] += wvals[t];
  }
  __syncthreads();
  if (tid == 0) comb[row] = 0.0f;
  __syncthreads();
  const int kk = s2v[row];
  const size_t obase = (size_t)row * NN;
  if (kk <= 0) {
    for (int j = tid * 4; j < NN; j += 2048)
      __builtin_nontemporal_store(z4, reinterpret_cast<f32x4*>(&out1[obase + j]));
    return;
  }
  // --- radix select: kk-th largest of comb. All values >= 0 -> uint order.
  // Threshold provably > 0, so zero entries are skipped.
  unsigned int prefix = 0u;
  int remaining = kk;
  for (int pass = 0; pass < 4; ++pass) {
    const int shift = 24 - 8 * pass;
    const unsigned int pmask = (pass == 0) ? 0u : (0xFFFFFFFFu << (shift + 8));
    if (tid < 256) hist[tid] = 0u;
    __syncthreads();
    for (int j = tid * 4; j < NN; j += 2048) {
      const f32x4 cv = *reinterpret_cast<const f32x4*>(&comb[j]);
#pragma unroll
      for (int q = 0; q < 4; ++q) {
        const unsigned int u = __float_as_uint(cv[q]);
        if (u != 0u && (u & pmask) == prefix)
          atomicAdd(&hist[(u >> shift) & 255u], 1u);
      }
    }
    __syncthreads();
    if (tid < 64) {
      const int bHi = 255 - 4 * lane;  // lane 0 owns highest bins
      const unsigned int c0 = hist[bHi];
      const unsigned int c1 = hist[bHi - 1];
      const unsigned int c2 = hist[bHi - 2];
      const unsigned int c3 = hist[bHi - 3];
      const unsigned int gs = c0 + c1 + c2 + c3;
      unsigned int run2 = gs;
      for (int o = 1; o < 64; o <<= 1) {
        const unsigned int tt = __shfl_up(run2, o);
        if (lane >= o) run2 += tt;
      }
      const unsigned int pre = run2 - gs;  // count in strictly higher bins
      const unsigned int rem = (unsigned int)remaining;
      if (pre < rem && pre + gs >= rem) {  // exactly one lane hits
        unsigned int above;
        int digit;
        if (pre + c0 >= rem) { digit = bHi; above = pre; }
        else if (pre + c0 + c1 >= rem) { digit = bHi - 1; above = pre + c0; }
        else if (pre + c0 + c1 + c2 >= rem) { digit = bHi - 2; above = pre + c0 + c1; }
        else { digit = bHi - 3; above = pre + c0 + c1 + c2; }
        shPrefix = prefix | ((unsigned int)digit << shift);
        shRemaining = remaining - (int)above;
      }
    }
    __syncthreads();
    prefix = shPrefix;
    remaining = shRemaining;
    __syncthreads();
  }
  const float thr = __uint_as_float(prefix);  // exact kk-th largest value
  for (int j = tid * 4; j < NN; j += 2048) {
    const f32x4 cv = *reinterpret_cast<const f32x4*>(&comb[j]);
    f32x4 ov;
    ov[0] = (cv[0] >= thr && cv[0] > 0.0f) ? 1.0f : 0.0f;
    ov[1] = (cv[1] >= thr && cv[1] > 0.0f) ? 1.0f : 0.0f;
    ov[2] = (cv[2] >= thr && cv[2] > 0.0f) ? 1.0f : 0.0f;
    ov[3] = (cv[3] >= thr && cv[3] > 0.0f) ? 1.0f : 0.0f;
    __builtin_nontemporal_store(ov, reinterpret_cast<f32x4*>(&out1[obase + j]));
  }
}

// ---------------------------------------------------------------------------
// Kernel F: h_prime = attention @ Wh (sparse x dense), then ELU.
// ---------------------------------------------------------------------------
__global__ void __launch_bounds__(256) k_hprime(
    const int* __restrict__ nbr, const int* __restrict__ deg,
    const float* __restrict__ att, const float* __restrict__ Wh,
    float* __restrict__ out0) {
  __shared__ int scol[MAXD];
  __shared__ float sval[MAXD];
  const int row = blockIdx.x;
  const int c = threadIdx.x;
  const int d = deg[row];
  const int* cols = nbr + (size_t)row * MAXD;
  const float* arow = att + (size_t)row * MAXD;
  for (int t = threadIdx.x; t < d; t += 256) {
    scol[t] = cols[t];
    sval[t] = arow[t];
  }
  __syncthreads();
  float a0 = 0.0f, a1 = 0.0f, a2 = 0.0f, a3 = 0.0f;
  int t = 0;
  for (; t + 4 <= d; t += 4) {
    a0 += sval[t + 0] * Wh[(size_t)scol[t + 0] * KFOUT + c];
    a1 += sval[t + 1] * Wh[(size_t)scol[t + 1] * KFOUT + c];
    a2 += sval[t + 2] * Wh[(size_t)scol[t + 2] * KFOUT + c];
    a3 += sval[t + 3] * Wh[(size_t)scol[t + 3] * KFOUT + c];
  }
  for (; t < d; ++t) a0 += sval[t] * Wh[(size_t)scol[t] * KFOUT + c];
  const float acc = (a0 + a1) + (a2 + a3);
  out0[(size_t)row * KFOUT + c] = acc > 0.0f ? acc : expm1f(acc);
}

extern "C" void kernel_launch(void* const* d_in, const int* in_sizes, int n_in,
                              void* d_out, int out_size, void* d_ws, size_t ws_size,
                              hipStream_t stream) {
  const float* h = (const float*)d_in[0];
  const float* adj = (const float*)d_in[1];
  const float* W = (const float*)d_in[2];
  const float* a = (const float*)d_in[3];

  float* out0 = (float*)d_out;                  // [8192, 256] elu(h_prime)
  float* out1 = out0 + (size_t)NN * KFOUT;      // [8192, 8192] adj_resize

  // workspace layout (~33.9 MB)
  float* Wh = (float*)d_ws;                        // 8192*256
  float* Wh1 = Wh + (size_t)NN * KFOUT;            // 8192
  float* Wh2 = Wh1 + NN;                           // 8192
  float* mrow = Wh2 + NN;                          // 8192
  float* Zrow = mrow + NN;                         // 8192
  float* att = Zrow + NN;                          // 8192*MAXD
  float* edgesF = att + (size_t)NN * MAXD;         // 8192*MAXD int2
  int2* edgesT = (int2*)edgesF;
  int* nbr = (int*)(edgesF + (size_t)NN * MAXD * 2);  // 8192*MAXD
  int* deg = nbr + (size_t)NN * MAXD;              // 8192
  int* s2v = deg + NN;                             // 8192
  short* qb8 = (short*)(s2v + NN);                 // 8192*8 shorts (128 KB)

  k_build_csr<<<NN / 4, 256, 0, stream>>>(adj, nbr, deg, s2v);
  dim3 ggrid(KFOUT / 64, NN / 64);
  k_gemm<<<ggrid, 256, 0, stream>>>(h, W, Wh);
  k_rowdots<<<NN, 256, 0, stream>>>(Wh, a, Wh1, Wh2);
  k_stats<<<NN / 4, 256, 0, stream>>>(nbr, deg, Wh1, Wh2, mrow, Zrow);
  k_att<<<NN / 4, 256, 0, stream>>>(nbr, deg, Wh1, Wh2, mrow, Zrow, att, edgesT, qb8);
  k_twostep<<<NN, 512, 0, stream>>>(nbr, deg, s2v, att, edgesT, qb8, out1);
  k_hprime<<<NN, 256, 0, stream>>>(nbr, deg, att, Wh, out0);
}